// Round 8
// baseline (298.226 us; speedup 1.0000x reference)
//
#include <hip/hip_runtime.h>

#define EMBED 768
#define NH 12
#define HD 64
#define MEMN 64
#define BB 8
#define TT 1024
#define ROWS 8192
#define QKV_N 2304
#define QSZ 6291456           // B*T*C = B*NH*TT*HD (elements)

typedef short bf16x8_t __attribute__((ext_vector_type(8)));
typedef float f32x4_t __attribute__((ext_vector_type(4)));

__device__ __forceinline__ unsigned short f2b(float f){
    union { float f; unsigned int i; } v; v.f = f;
    unsigned int x = v.i;
    unsigned int r = x + 0x7fffu + ((x >> 16) & 1u);
    return (unsigned short)(r >> 16);
}
// round-half-up convert for non-negative values (softmax p)
__device__ __forceinline__ unsigned short f2b_ru(float f){
    union { float f; unsigned int i; } v; v.f = f;
    return (unsigned short)((v.i + 0x8000u) >> 16);
}

// async global->LDS, 16B per lane; lds base must be wave-uniform (lane*16 implicit)
__device__ __forceinline__ void gl16(const unsigned short* g, unsigned short* l){
    __builtin_amdgcn_global_load_lds(
        (const __attribute__((address_space(1))) void*)g,
        (__attribute__((address_space(3))) void*)l,
        16, 0, 0);
}

#define SCHED_FENCE() __builtin_amdgcn_sched_barrier(0)

// ---- fused prep: x cvt + w_qkv tcvt + w_out tcvt + memproj (one graph node) ----
#define PREP_CVT   3072
#define PREP_TQKV  4800
#define PREP_TOUT  5376
#define PREP_TOTAL 5388

__global__ __launch_bounds__(256) void prep_kernel(
    const float* __restrict__ x,
    const float* __restrict__ w_qkv,
    const float* __restrict__ w_out,
    const float* __restrict__ memory,
    const float* __restrict__ w_mem,
    const float* __restrict__ b_mem,
    unsigned short* __restrict__ xb,
    unsigned short* __restrict__ wqkvT,
    unsigned short* __restrict__ woutT,
    unsigned short* __restrict__ mem_k,
    unsigned short* __restrict__ mem_v)
{
    __shared__ unsigned short pool[5120];
    const int bid = blockIdx.x;
    const int t = threadIdx.x;

    if (bid < PREP_CVT) {
        int i = bid * 2048 + t * 8;
        float4 f0 = *(const float4*)&x[i];
        float4 f1 = *(const float4*)&x[i + 4];
        union { bf16x8_t v; unsigned short s[8]; } u;
        u.s[0] = f2b(f0.x); u.s[1] = f2b(f0.y); u.s[2] = f2b(f0.z); u.s[3] = f2b(f0.w);
        u.s[4] = f2b(f1.x); u.s[5] = f2b(f1.y); u.s[6] = f2b(f1.z); u.s[7] = f2b(f1.w);
        *(bf16x8_t*)&xb[i] = u.v;
    } else if (bid < PREP_TOUT) {
        const float* in; unsigned short* out; int R, C, loc;
        if (bid < PREP_TQKV) { in = w_qkv; out = wqkvT; R = EMBED; C = QKV_N; loc = bid - PREP_CVT; }
        else                 { in = w_out; out = woutT; R = EMBED; C = EMBED; loc = bid - PREP_TQKV; }
        int nbc = C / 32;
        int bc = (loc % nbc) * 32, br = (loc / nbc) * 32;
        unsigned short (*tile)[33] = (unsigned short(*)[33])pool;
        int lr = t >> 5, lc = t & 31;
        for (int i = 0; i < 4; i++) {
            int r = lr + i * 8;
            tile[r][lc] = f2b(in[(size_t)(br + r) * C + bc + lc]);
        }
        __syncthreads();
        for (int i = 0; i < 4; i++) {
            int r = lr + i * 8;
            out[(size_t)(bc + r) * R + br + lc] = tile[lc][r];
        }
    } else {
        unsigned short (*As)[40] = (unsigned short(*)[40])pool;
        unsigned short (*Bs)[40] = (unsigned short(*)[40])(pool + 2560);
        int wave = t >> 6, lane = t & 63;
        int ln = lane & 15, lq = lane >> 4;
        int bn = (bid - PREP_TOUT) * 64;
        const int K = EMBED, N = EMBED;

        f32x4_t acc[4];
        for (int i = 0; i < 4; i++) acc[i] = (f32x4_t)(0.f);
        int sm = t >> 2, sk = (t & 3) * 8;
        int bk = t >> 3, bn8 = (t & 7) * 8;

        for (int k0 = 0; k0 < K; k0 += 32) {
            __syncthreads();
            {
                float4 f0 = *(const float4*)&memory[(size_t)sm * K + k0 + sk];
                float4 f1 = *(const float4*)&memory[(size_t)sm * K + k0 + sk + 4];
                unsigned short* ap = &As[sm][sk];
                ap[0] = f2b(f0.x); ap[1] = f2b(f0.y); ap[2] = f2b(f0.z); ap[3] = f2b(f0.w);
                ap[4] = f2b(f1.x); ap[5] = f2b(f1.y); ap[6] = f2b(f1.z); ap[7] = f2b(f1.w);
            }
            {
                float4 g0 = *(const float4*)&w_mem[(size_t)(k0 + bk) * N + bn + bn8];
                float4 g1 = *(const float4*)&w_mem[(size_t)(k0 + bk) * N + bn + bn8 + 4];
                Bs[bn8 + 0][bk] = f2b(g0.x); Bs[bn8 + 1][bk] = f2b(g0.y);
                Bs[bn8 + 2][bk] = f2b(g0.z); Bs[bn8 + 3][bk] = f2b(g0.w);
                Bs[bn8 + 4][bk] = f2b(g1.x); Bs[bn8 + 5][bk] = f2b(g1.y);
                Bs[bn8 + 6][bk] = f2b(g1.z); Bs[bn8 + 7][bk] = f2b(g1.w);
            }
            __syncthreads();
            bf16x8_t a = *(bf16x8_t*)&As[wave * 16 + ln][lq * 8];
            for (int nt = 0; nt < 4; nt++) {
                bf16x8_t bf = *(bf16x8_t*)&Bs[nt * 16 + ln][lq * 8];
                acc[nt] = __builtin_amdgcn_mfma_f32_16x16x32_bf16(a, bf, acc[nt], 0, 0, 0);
            }
        }
        for (int nt = 0; nt < 4; nt++) {
            int c = bn + nt * 16 + ln;
            float bv = b_mem[c];
            for (int r = 0; r < 4; r++) {
                int row = wave * 16 + lq * 4 + r;
                int h = c >> 6, d = c & 63;
                unsigned short o = f2b(acc[nt][r] + bv);
                mem_k[((h * 64 + row) << 6) + d] = o;   // [H,M,D]
                mem_v[((h * 64 + d) << 6) + row] = o;   // [H,D,M]
            }
        }
    }
}

// ---- 256x128 bf16 GEMM (r14 structure, verified): 48KB single-buffer,
// 2-barrier drain loop, XCD swizzle, LDS-bounce coalesced epilogue.
// r16: V output range written directly in transposed [B,H,D,T] (vtrans deleted). ----
__global__ __launch_bounds__(512) void gemm512(
    const unsigned short* __restrict__ A,
    const unsigned short* __restrict__ BT,
    const float* __restrict__ bias,
    unsigned short* __restrict__ dq,
    unsigned short* __restrict__ dkv,   // k at +0 ([B,H,T,D]); v at +QSZ ([B,H,D,T])
    int M, int N, int K)   // K == 768 always
{
    __shared__ unsigned short As[16384];  // 256 x 64
    __shared__ unsigned short Bs[8192];   // 128 x 64
    const int t = threadIdx.x;
    const int wave = t >> 6, lane = t & 63;
    const int ln = lane & 15, lq = lane >> 4;
    const int wm = (wave >> 1) * 64, wn = (wave & 1) * 64;

    // bijective XCD remap (576 = 8*72 exact)
    int bid0 = blockIdx.y * gridDim.x + blockIdx.x;
    int bid = (bid0 & 7) * 72 + (bid0 >> 3);
    int by = bid / 18, bx = bid - by * 18;
    const int bm = by * 256, bn = bx * 128;

    f32x4_t acc[4][4];
    for (int i = 0; i < 4; i++)
        for (int j = 0; j < 4; j++) acc[i][j] = (f32x4_t)(0.f);

    const int rl8 = lane >> 3;
    const int swz = ((lane & 7) ^ rl8) * 8;
    const unsigned short* Ap = A + (size_t)(bm + wave * 32 + rl8) * 768 + swz;
    const unsigned short* Bp = BT + (size_t)(bn + wave * 16 + rl8) * 768 + swz;
    unsigned short* asd = &As[wave * 2048];
    unsigned short* bsd = &Bs[wave * 1024];

    const int e0 = (lq ^ (ln & 7)) * 8;
    const int e1 = e0 ^ 32;

    for (int k0 = 0; k0 < 768; k0 += 64) {
        __syncthreads();
        for (int i = 0; i < 4; i++)
            gl16(Ap + (size_t)(i * 8) * 768 + k0, asd + i * 512);
        for (int i = 0; i < 2; i++)
            gl16(Bp + (size_t)(i * 8) * 768 + k0, bsd + i * 512);
        __syncthreads();

        {
            bf16x8_t af[4], bfr[4];
            for (int mt = 0; mt < 4; mt++)
                af[mt] = *(bf16x8_t*)&As[(wm + mt * 16 + ln) * 64 + e0];
            for (int nt = 0; nt < 4; nt++)
                bfr[nt] = *(bf16x8_t*)&Bs[(wn + nt * 16 + ln) * 64 + e0];
            for (int mt = 0; mt < 4; mt++)
                for (int nt = 0; nt < 4; nt++)
                    acc[mt][nt] = __builtin_amdgcn_mfma_f32_16x16x32_bf16(
                        af[mt], bfr[nt], acc[mt][nt], 0, 0, 0);
        }
        {
            bf16x8_t af[4], bfr[4];
            for (int mt = 0; mt < 4; mt++)
                af[mt] = *(bf16x8_t*)&As[(wm + mt * 16 + ln) * 64 + e1];
            for (int nt = 0; nt < 4; nt++)
                bfr[nt] = *(bf16x8_t*)&Bs[(wn + nt * 16 + ln) * 64 + e1];
            for (int mt = 0; mt < 4; mt++)
                for (int nt = 0; nt < 4; nt++)
                    acc[mt][nt] = __builtin_amdgcn_mfma_f32_16x16x32_bf16(
                        af[mt], bfr[nt], acc[mt][nt], 0, 0, 0);
        }
    }

    // ---- LDS-bounce coalesced epilogue ----
    __syncthreads();                       // all waves done reading As/Bs
    unsigned short* slab = &As[wave * 2048];   // wave-private 4KB (32 rows x 64)
    const float QSCALE = 0.125f * 1.44269504088896340736f;
    const int s = bn / 768;                // block-uniform: 768 % 128 == 0
    const int rem0 = bn + wn - s * 768;
    const int h = rem0 >> 6;               // head index (s>=1); rem0 is 64-aligned
    const int bbq = bm >> 10;              // batch (256-row tile never crosses b)
    const int tt0 = (bm & 1023) + wm;
    const int r2 = lane >> 1, half = lane & 1;

    float bv[4];
    for (int nt = 0; nt < 4; nt++) bv[nt] = bias[bn + wn + nt * 16 + ln];

    for (int p = 0; p < 2; p++) {
        // scatter this wave's acc (mt = 2p, 2p+1) into swizzled slab [32][64]
        for (int mt2 = 0; mt2 < 2; mt2++) {
            int mt = p * 2 + mt2;
            for (int nt = 0; nt < 4; nt++) {
                int col = nt * 16 + ln;
                for (int r = 0; r < 4; r++) {
                    int tp = mt2 * 16 + lq * 4 + r;
                    float val = acc[mt][nt][r] + bv[nt];
                    if (s == 0) val *= QSCALE;
                    slab[tp * 64 + ((((col >> 3) ^ (tp & 7)) << 3) | (col & 7))] = f2b(val);
                }
            }
        }
        asm volatile("s_waitcnt lgkmcnt(0)" ::: "memory");  // wave-local slab visible
        SCHED_FENCE();
        if (s == 0) {
            // q: row-gather, coalesced bf16x8 stores
            unsigned short* op = dq + (size_t)(bm + wm + p * 32 + r2) * 768 + bn + wn;
#pragma unroll
            for (int i = 0; i < 4; i++) {
                int c2 = half * 4 + i;
                int g = c2 ^ (r2 & 7);
                *(bf16x8_t*)&op[c2 * 8] = *(bf16x8_t*)&slab[r2 * 64 + g * 8];
            }
        } else if (s == 1) {
            // k: [B,H,T,D], row-gather
            unsigned short* op = dkv +
                (((size_t)(bbq * 12 + h) * 1024 + tt0 + p * 32 + r2) << 6);
#pragma unroll
            for (int i = 0; i < 4; i++) {
                int c2 = half * 4 + i;
                int g = c2 ^ (r2 & 7);
                *(bf16x8_t*)&op[c2 * 8] = *(bf16x8_t*)&slab[r2 * 64 + g * 8];
            }
        } else {
            // v: direct transposed [B,H,D,T] (replaces the vtrans kernel)
            unsigned short* op0 = dkv + (size_t)QSZ + (((size_t)(bbq * 12 + h)) << 16);
            const int tb = tt0 + p * 32;
#pragma unroll
            for (int i = 0; i < 4; i++) {
                int d = (lane >> 2) + i * 16;
                int t0q = (lane & 3) * 8;
                union { bf16x8_t v; unsigned short s8[8]; } u;
#pragma unroll
                for (int j = 0; j < 8; j++) {
                    int tp = t0q + j;
                    u.s8[j] = slab[tp * 64 + ((((d >> 3) ^ (tp & 7)) << 3) | (d & 7))];
                }
                *(bf16x8_t*)&op0[d * 1024 + tb + t0q] = u.v;
            }
        }
        SCHED_FENCE();   // keep p=1 slab writes after p=0 reads (in-order DS per wave)
    }
}

// ---- 128x128 bf16 GEMM, BK=64, XOR-swizzled, double-buffered,
// r12 counted-vmcnt 2-deep pipeline; r14 LDS-bounce f32 epilogue. ----
__global__ __launch_bounds__(256) void gemm_bt(
    const unsigned short* __restrict__ A,
    const unsigned short* __restrict__ BT,
    const float* __restrict__ bias,
    float* __restrict__ df,
    int M, int N, int K)   // K == 768 always
{
    __shared__ unsigned short As[2][8192];   // 2 x (128 x 64)
    __shared__ unsigned short Bs[2][8192];
    const int t = threadIdx.x;
    const int wave = t >> 6, lane = t & 63;
    const int ln = lane & 15, lq = lane >> 4;
    const int wm = (wave >> 1) * 64, wn = (wave & 1) * 64;
    const int bm = blockIdx.y * 128, bn = blockIdx.x * 128;

    f32x4_t acc[4][4];
    for (int i = 0; i < 4; i++)
        for (int j = 0; j < 4; j++) acc[i][j] = (f32x4_t)(0.f);

    const int rl8 = lane >> 3;
    const int swz = ((lane & 7) ^ rl8) * 8;
    const unsigned short* Ap = A + (size_t)(bm + wave * 32 + rl8) * 768 + swz;
    const unsigned short* Bp = BT + (size_t)(bn + wave * 32 + rl8) * 768 + swz;

    const int e0 = (lq ^ (ln & 7)) * 8;
    const int e1 = e0 ^ 32;

    auto stage = [&](int buf, int k0) {
#pragma unroll
        for (int i = 0; i < 4; i++) {
            gl16(Ap + (size_t)(i * 8) * 768 + k0, &As[buf][wave * 2048 + i * 512]);
            gl16(Bp + (size_t)(i * 8) * 768 + k0, &Bs[buf][wave * 2048 + i * 512]);
        }
    };

    auto compute = [&](const unsigned short* Ac, const unsigned short* Bc) {
        bf16x8_t af0[4], af1[4], bf0[4], bf1[4];
#pragma unroll
        for (int mt = 0; mt < 4; mt++) {
            af0[mt] = *(const bf16x8_t*)&Ac[(wm + mt * 16 + ln) * 64 + e0];
            af1[mt] = *(const bf16x8_t*)&Ac[(wm + mt * 16 + ln) * 64 + e1];
        }
#pragma unroll
        for (int nt = 0; nt < 4; nt++) {
            bf0[nt] = *(const bf16x8_t*)&Bc[(wn + nt * 16 + ln) * 64 + e0];
            bf1[nt] = *(const bf16x8_t*)&Bc[(wn + nt * 16 + ln) * 64 + e1];
        }
        __builtin_amdgcn_s_setprio(1);
#pragma unroll
        for (int mt = 0; mt < 4; mt++)
#pragma unroll
            for (int nt = 0; nt < 4; nt++)
                acc[mt][nt] = __builtin_amdgcn_mfma_f32_16x16x32_bf16(
                    af0[mt], bf0[nt], acc[mt][nt], 0, 0, 0);
#pragma unroll
        for (int mt = 0; mt < 4; mt++)
#pragma unroll
            for (int nt = 0; nt < 4; nt++)
                acc[mt][nt] = __builtin_amdgcn_mfma_f32_16x16x32_bf16(
                    af1[mt], bf1[nt], acc[mt][nt], 0, 0, 0);
        __builtin_amdgcn_s_setprio(0);
    };

    // prologue: tiles 0,1 in flight (16 loads), wait tile 0
    stage(0, 0);
    stage(1, 64);
    SCHED_FENCE();
    asm volatile("s_waitcnt vmcnt(8)" ::: "memory");
    SCHED_FENCE();
    __builtin_amdgcn_s_barrier();
    SCHED_FENCE();

#pragma unroll 2
    for (int tt = 0; tt < 10; ++tt) {
        const int cur = tt & 1;
        compute(&As[cur][0], &Bs[cur][0]);
        SCHED_FENCE();
        __builtin_amdgcn_s_barrier();
        SCHED_FENCE();
        stage(cur, (tt + 2) * 64);
        SCHED_FENCE();
        asm volatile("s_waitcnt vmcnt(8)" ::: "memory");
        SCHED_FENCE();
        __builtin_amdgcn_s_barrier();
        SCHED_FENCE();
    }
    compute(&As[0][0], &Bs[0][0]);
    SCHED_FENCE();
    asm volatile("s_waitcnt vmcnt(0)" ::: "memory");
    SCHED_FENCE();
    __builtin_amdgcn_s_barrier();
    SCHED_FENCE();
    compute(&As[1][0], &Bs[1][0]);

    // ---- LDS-bounce coalesced f32 epilogue ----
    __syncthreads();                           // all waves done with As/Bs
    float* slabf = (float*)&As[0][0] + wave * 2048;   // wave-private 8KB (32 x 64 f32)
    const int r2 = lane >> 1, half = lane & 1;
    float bv[4];
    for (int nt = 0; nt < 4; nt++) bv[nt] = bias[bn + wn + nt * 16 + ln];

    for (int p = 0; p < 2; p++) {
        for (int mt2 = 0; mt2 < 2; mt2++) {
            int mt = p * 2 + mt2;
            for (int nt = 0; nt < 4; nt++) {
                int col = nt * 16 + ln;
                for (int r = 0; r < 4; r++) {
                    int tp = mt2 * 16 + lq * 4 + r;
                    slabf[tp * 64 + ((((col >> 2) ^ (tp & 15)) << 2) | (col & 3))] =
                        acc[mt][nt][r] + bv[nt];
                }
            }
        }
        asm volatile("s_waitcnt lgkmcnt(0)" ::: "memory");
        SCHED_FENCE();
        float* op = df + (size_t)(bm + wm + p * 32 + r2) * 768 + bn + wn;
#pragma unroll
        for (int i = 0; i < 8; i++) {
            int c2 = half * 8 + i;
            int g = c2 ^ (r2 & 15);
            *(float4*)&op[c2 * 4] = *(float4*)&slabf[r2 * 64 + g * 4];
        }
        SCHED_FENCE();
    }
}

// ---- flash attention r18: r14 structure (512 thr, 8 waves x 16 q-rows,
// 24 waves/CU TLP — r17's 4-wave variant lost occupancy 33->16% and regressed),
// with V REMOVED FROM LDS: V B-fragments load directly from global.
// Mechanism: fragment addr (d=nt*16+ln, k=lq*8) has NO wave term -> all 8
// waves read identical addresses -> 1st wave L2-miss, rest L1-hit; each load
// inst = 16 coalesced 64B segments; V per (b,h) = 128KB, L2-resident on the
// block's XCD (existing swizzle). De-swizzled map: LDS e0 chunk == global
// k = kt*128+half*64+lq*8; e1 == +32. DS b128/wave/kt: 36 -> 20 (618->426cyc,
// per-CU floor 49 -> 34us). K staging, P path, mem-attn unchanged from r14. ----
__global__ __launch_bounds__(512) void attn_kernel(
    unsigned short* __restrict__ qio,           // [B,T,768] bf16, in/out (q pre-scaled)
    const unsigned short* __restrict__ k_ws,    // [B,H,T,D] bf16
    const unsigned short* __restrict__ vT_ws,   // [B,H,D,T] bf16 (transposed)
    const unsigned short* __restrict__ mem_k,   // [H,M,D]   bf16
    const unsigned short* __restrict__ mem_v)   // [H,D,M]   bf16
{
    __shared__ unsigned short Qs[8192];   // 128x64; aliased as Ps after frag hoist
    __shared__ unsigned short Ks[8192];   // two 64-key tiles
    __shared__ unsigned short Vs[8192];   // mem-attn staging only (kt loop: V direct)
    unsigned short* Ps = Qs;

    const int t = threadIdx.x;
    const int wave = t >> 6, lane = t & 63;
    const int ln = lane & 15, lq = lane >> 4;
    const int rl = lane >> 3;
    const int cl = ((lane & 7) ^ rl) * 8;

    // XCD swizzle: 8 q-tiles of one (b,h) land on one XCD
    int bid = blockIdx.x;
    int xcd = bid & 7, rest = bid >> 3;        // rest 0..95
    int bh = xcd * 12 + (rest >> 3);           // 0..95 == b*NH + h
    int qt = rest & 7;                         // 0..7 (128-row q tiles)
    int b = bh / 12, h = bh - b * 12;

    unsigned short* qp = qio + ((size_t)(b * TT + qt * 128)) * 768 + h * 64;
    const unsigned short* kp = k_ws + (size_t)bh * TT * 64;
    const unsigned short* vp = vT_ws + ((size_t)bh << 16);
    const unsigned short* mkp = mem_k + h * 4096;
    const unsigned short* mvp = mem_v + h * 4096;

    // stage Q (2 slabs per wave), hoist this wave's A-fragments (16 q-rows)
    {
        const unsigned short* qg = qp + (size_t)(wave * 16 + rl) * 768 + cl;
        gl16(qg, &Qs[wave * 1024]);
        gl16(qg + (size_t)8 * 768, &Qs[wave * 1024 + 512]);
    }
    __syncthreads();
    const int e0 = (lq ^ (ln & 7)) * 8;
    const int e1 = ((lq ^ (ln & 7)) ^ 4) * 8;
    bf16x8_t aq0 = *(bf16x8_t*)&Qs[(wave * 16 + ln) * 64 + e0];
    bf16x8_t aq1 = *(bf16x8_t*)&Qs[(wave * 16 + ln) * 64 + e1];

    // K staging base (unchanged); V direct-load base: row d = nt*16+ln, col lq*8
    const unsigned short* kg = kp + (wave * 16 + rl) * 64 + cl;
    const unsigned short* vrow = vp + (size_t)ln * 1024 + lq * 8;

    const int hi3 = ln >> 3, lo3 = ln & 7;
    const int pm = (lq & 1) << 2;
    const int pw0 = (wave * 16 + lq * 4) * 64 + lo3;

    float lsum[4] = {0.f, 0.f, 0.f, 0.f};
    f32x4_t accO[4];
    for (int nt = 0; nt < 4; nt++) accO[nt] = (f32x4_t)(0.f);

    for (int kt = 0; kt < 8; kt++) {
        __syncthreads();
        gl16(kg + kt * 8192,        &Ks[wave * 1024]);
        gl16(kg + kt * 8192 + 512,  &Ks[wave * 1024 + 512]);
        __syncthreads();

        for (int half = 0; half < 2; half++) {
            const unsigned short* Kh = &Ks[half * 4096];
            // issue V fragment loads early: latency hides under QK + softmax
            const unsigned short* vh = vrow + kt * 128 + half * 64;
            bf16x8_t vf0[4], vf1[4];
#pragma unroll
            for (int nt = 0; nt < 4; nt++) {
                vf0[nt] = *(const bf16x8_t*)&vh[(size_t)(nt * 16) * 1024];
                vf1[nt] = *(const bf16x8_t*)&vh[(size_t)(nt * 16) * 1024 + 32];
            }
            f32x4_t s[4];
            for (int nt = 0; nt < 4; nt++) s[nt] = (f32x4_t)(0.f);
            for (int nt = 0; nt < 4; nt++)
                s[nt] = __builtin_amdgcn_mfma_f32_16x16x32_bf16(
                    aq0, *(bf16x8_t*)&Kh[(nt * 16 + ln) * 64 + e0], s[nt], 0, 0, 0);
            for (int nt = 0; nt < 4; nt++)
                s[nt] = __builtin_amdgcn_mfma_f32_16x16x32_bf16(
                    aq1, *(bf16x8_t*)&Kh[(nt * 16 + ln) * 64 + e1], s[nt], 0, 0, 0);

            for (int nt = 0; nt < 4; nt++) {
                for (int r = 0; r < 4; r++) {
                    float p = __builtin_amdgcn_exp2f(s[nt][r]);
                    lsum[r] += p;
                    int chp = (nt * 2 + hi3) ^ pm ^ r;
                    Ps[pw0 + r * 64 + chp * 8] = f2b_ru(p);
                }
            }
            // Ps slab is wave-private: no barrier needed
            bf16x8_t a0 = *(bf16x8_t*)&Ps[(wave * 16 + ln) * 64 + e0];
            bf16x8_t a1 = *(bf16x8_t*)&Ps[(wave * 16 + ln) * 64 + e1];
            for (int nt = 0; nt < 4; nt++) {
                accO[nt] = __builtin_amdgcn_mfma_f32_16x16x32_bf16(
                    a0, vf0[nt], accO[nt], 0, 0, 0);
                accO[nt] = __builtin_amdgcn_mfma_f32_16x16x32_bf16(
                    a1, vf1[nt], accO[nt], 0, 0, 0);
            }
        }
    }

    // memory attention: 64 projected keys (each wave stages 1 slab of K and V)
    __syncthreads();
    gl16(mkp + (wave * 8 + rl) * 64 + cl, &Ks[wave * 512]);
    gl16(mvp + (wave * 8 + rl) * 64 + cl, &Vs[wave * 512]);
    __syncthreads();

    f32x4_t s2[4];
    for (int nt = 0; nt < 4; nt++) s2[nt] = (f32x4_t)(0.f);
    for (int nt = 0; nt < 4; nt++)
        s2[nt] = __builtin_amdgcn_mfma_f32_16x16x32_bf16(
            aq0, *(bf16x8_t*)&Ks[(nt * 16 + ln) * 64 + e0], s2[nt], 0, 0, 0);
    for (int nt = 0; nt < 4; nt++)
        s2[nt] = __builtin_amdgcn_mfma_f32_16x16x32_bf16(
            aq1, *(bf16x8_t*)&Ks[(nt * 16 + ln) * 64 + e1], s2[nt], 0, 0, 0);

    float l2[4] = {0.f, 0.f, 0.f, 0.f};
    for (int nt = 0; nt < 4; nt++) {
        for (int r = 0; r < 4; r++) {
            float p = __builtin_amdgcn_exp2f(s2[nt][r]);
            l2[r] += p;
            int chp = (nt * 2 + hi3) ^ pm ^ r;
            Ps[pw0 + r * 64 + chp * 8] = f2b_ru(p);
        }
    }
    f32x4_t accM[4];
    for (int nt = 0; nt < 4; nt++) accM[nt] = (f32x4_t)(0.f);
    {
        bf16x8_t a0 = *(bf16x8_t*)&Ps[(wave * 16 + ln) * 64 + e0];
        bf16x8_t a1 = *(bf16x8_t*)&Ps[(wave * 16 + ln) * 64 + e1];
        for (int nt = 0; nt < 4; nt++) {
            accM[nt] = __builtin_amdgcn_mfma_f32_16x16x32_bf16(
                a0, *(bf16x8_t*)&Vs[(nt * 16 + ln) * 64 + e0], accM[nt], 0, 0, 0);
            accM[nt] = __builtin_amdgcn_mfma_f32_16x16x32_bf16(
                a1, *(bf16x8_t*)&Vs[(nt * 16 + ln) * 64 + e1], accM[nt], 0, 0, 0);
        }
    }

    float inv[4], inv2[4];
    for (int r = 0; r < 4; r++) {
        float a = lsum[r], c = l2[r];
        a += __shfl_xor(a, 1); a += __shfl_xor(a, 2);
        a += __shfl_xor(a, 4); a += __shfl_xor(a, 8);
        c += __shfl_xor(c, 1); c += __shfl_xor(c, 2);
        c += __shfl_xor(c, 4); c += __shfl_xor(c, 8);
        inv[r] = 1.f / a;
        inv2[r] = 1.f / c;
    }

    for (int nt = 0; nt < 4; nt++) {
        for (int r = 0; r < 4; r++) {
            int lrow = wave * 16 + lq * 4 + r;
            int lcol = nt * 16 + ln;
            float val = accO[nt][r] * inv[r] + accM[nt][r] * inv2[r];
            qp[(size_t)lrow * 768 + lcol] = f2b(val);
        }
    }
}

// ---------------- host ----------------
extern "C" void kernel_launch(void* const* d_in, const int* in_sizes, int n_in,
                              void* d_out, int out_size, void* d_ws, size_t ws_size,
                              hipStream_t stream) {
    const float* x      = (const float*)d_in[0];
    const float* w_qkv  = (const float*)d_in[1];
    const float* b_qkv  = (const float*)d_in[2];
    const float* w_out  = (const float*)d_in[3];
    const float* b_out  = (const float*)d_in[4];
    const float* w_mem  = (const float*)d_in[5];
    const float* b_mem  = (const float*)d_in[6];
    const float* memory = (const float*)d_in[7];

    unsigned short* ws = (unsigned short*)d_ws;
    unsigned short* q_ws   = ws;                         // [B,T,C] bf16; attn in-place
    unsigned short* k_ws   = ws + (size_t)QSZ;           // [B,H,T,D]; vT at +QSZ ([B,H,D,T])
    unsigned short* vT     = ws + 2 * (size_t)QSZ;       // [B,H,D,T] (written by gemm512)
    unsigned short* woutT  = ws + 3 * (size_t)QSZ;       // [768][768] bf16 (N x K)
    unsigned short* mem_k  = woutT + (size_t)EMBED * EMBED;
    unsigned short* mem_v  = mem_k + (size_t)NH * MEMN * HD;

    unsigned short* xb    = (unsigned short*)d_out;      // [8192][768] bf16
    unsigned short* wqkvT = xb + (size_t)QSZ;            // [2304][768] bf16

    // 1) fused prep (cvt + 2 tcvt + memproj)
    prep_kernel<<<PREP_TOTAL, 256, 0, stream>>>(
        x, w_qkv, w_out, memory, w_mem, b_mem, xb, wqkvT, woutT, mem_k, mem_v);

    // 2) QKV projection: q -> q_ws; k -> [B,H,T,D]; v -> [B,H,D,T] (transposed direct)
    gemm512<<<dim3(QKV_N / 128, ROWS / 256), 512, 0, stream>>>(
        xb, wqkvT, b_qkv, q_ws, k_ws, ROWS, QKV_N, EMBED);

    // 3) attention (local flash + memory), in-place over q_ws; 768 blocks x 512 thr
    attn_kernel<<<8 * NH * BB, 512, 0, stream>>>(q_ws, k_ws, vT, mem_k, mem_v);

    // 4) output projection: q_ws(bf16) @ w_out + b_out -> d_out fp32
    gemm_bt<<<dim3(EMBED / 128, ROWS / 128), 256, 0, stream>>>(
        q_ws, woutT, b_out, (float*)d_out, ROWS, EMBED, EMBED);
}

// Round 9
// 233.314 us; speedup vs baseline: 1.2782x; 1.2782x over previous
//
#include <hip/hip_runtime.h>

#define EMBED 768
#define NH 12
#define HD 64
#define MEMN 64
#define BB 8
#define TT 1024
#define ROWS 8192
#define QKV_N 2304
#define QSZ 6291456           // B*T*C = B*NH*TT*HD (elements)

typedef short bf16x8_t __attribute__((ext_vector_type(8)));
typedef float f32x4_t __attribute__((ext_vector_type(4)));

__device__ __forceinline__ unsigned short f2b(float f){
    union { float f; unsigned int i; } v; v.f = f;
    unsigned int x = v.i;
    unsigned int r = x + 0x7fffu + ((x >> 16) & 1u);
    return (unsigned short)(r >> 16);
}
// round-half-up convert for non-negative values (softmax p)
__device__ __forceinline__ unsigned short f2b_ru(float f){
    union { float f; unsigned int i; } v; v.f = f;
    return (unsigned short)((v.i + 0x8000u) >> 16);
}

// async global->LDS, 16B per lane; lds base must be wave-uniform (lane*16 implicit)
__device__ __forceinline__ void gl16(const unsigned short* g, unsigned short* l){
    __builtin_amdgcn_global_load_lds(
        (const __attribute__((address_space(1))) void*)g,
        (__attribute__((address_space(3))) void*)l,
        16, 0, 0);
}

#define SCHED_FENCE() __builtin_amdgcn_sched_barrier(0)

// ---- fused prep: x cvt + w_qkv tcvt + w_out tcvt + memproj (one graph node) ----
#define PREP_CVT   3072
#define PREP_TQKV  4800
#define PREP_TOUT  5376
#define PREP_TOTAL 5388

__global__ __launch_bounds__(256) void prep_kernel(
    const float* __restrict__ x,
    const float* __restrict__ w_qkv,
    const float* __restrict__ w_out,
    const float* __restrict__ memory,
    const float* __restrict__ w_mem,
    const float* __restrict__ b_mem,
    unsigned short* __restrict__ xb,
    unsigned short* __restrict__ wqkvT,
    unsigned short* __restrict__ woutT,
    unsigned short* __restrict__ mem_k,
    unsigned short* __restrict__ mem_v)
{
    __shared__ unsigned short pool[5120];
    const int bid = blockIdx.x;
    const int t = threadIdx.x;

    if (bid < PREP_CVT) {
        int i = bid * 2048 + t * 8;
        float4 f0 = *(const float4*)&x[i];
        float4 f1 = *(const float4*)&x[i + 4];
        union { bf16x8_t v; unsigned short s[8]; } u;
        u.s[0] = f2b(f0.x); u.s[1] = f2b(f0.y); u.s[2] = f2b(f0.z); u.s[3] = f2b(f0.w);
        u.s[4] = f2b(f1.x); u.s[5] = f2b(f1.y); u.s[6] = f2b(f1.z); u.s[7] = f2b(f1.w);
        *(bf16x8_t*)&xb[i] = u.v;
    } else if (bid < PREP_TOUT) {
        const float* in; unsigned short* out; int R, C, loc;
        if (bid < PREP_TQKV) { in = w_qkv; out = wqkvT; R = EMBED; C = QKV_N; loc = bid - PREP_CVT; }
        else                 { in = w_out; out = woutT; R = EMBED; C = EMBED; loc = bid - PREP_TQKV; }
        int nbc = C / 32;
        int bc = (loc % nbc) * 32, br = (loc / nbc) * 32;
        unsigned short (*tile)[33] = (unsigned short(*)[33])pool;
        int lr = t >> 5, lc = t & 31;
        for (int i = 0; i < 4; i++) {
            int r = lr + i * 8;
            tile[r][lc] = f2b(in[(size_t)(br + r) * C + bc + lc]);
        }
        __syncthreads();
        for (int i = 0; i < 4; i++) {
            int r = lr + i * 8;
            out[(size_t)(bc + r) * R + br + lc] = tile[lc][r];
        }
    } else {
        unsigned short (*As)[40] = (unsigned short(*)[40])pool;
        unsigned short (*Bs)[40] = (unsigned short(*)[40])(pool + 2560);
        int wave = t >> 6, lane = t & 63;
        int ln = lane & 15, lq = lane >> 4;
        int bn = (bid - PREP_TOUT) * 64;
        const int K = EMBED, N = EMBED;

        f32x4_t acc[4];
        for (int i = 0; i < 4; i++) acc[i] = (f32x4_t)(0.f);
        int sm = t >> 2, sk = (t & 3) * 8;
        int bk = t >> 3, bn8 = (t & 7) * 8;

        for (int k0 = 0; k0 < K; k0 += 32) {
            __syncthreads();
            {
                float4 f0 = *(const float4*)&memory[(size_t)sm * K + k0 + sk];
                float4 f1 = *(const float4*)&memory[(size_t)sm * K + k0 + sk + 4];
                unsigned short* ap = &As[sm][sk];
                ap[0] = f2b(f0.x); ap[1] = f2b(f0.y); ap[2] = f2b(f0.z); ap[3] = f2b(f0.w);
                ap[4] = f2b(f1.x); ap[5] = f2b(f1.y); ap[6] = f2b(f1.z); ap[7] = f2b(f1.w);
            }
            {
                float4 g0 = *(const float4*)&w_mem[(size_t)(k0 + bk) * N + bn + bn8];
                float4 g1 = *(const float4*)&w_mem[(size_t)(k0 + bk) * N + bn + bn8 + 4];
                Bs[bn8 + 0][bk] = f2b(g0.x); Bs[bn8 + 1][bk] = f2b(g0.y);
                Bs[bn8 + 2][bk] = f2b(g0.z); Bs[bn8 + 3][bk] = f2b(g0.w);
                Bs[bn8 + 4][bk] = f2b(g1.x); Bs[bn8 + 5][bk] = f2b(g1.y);
                Bs[bn8 + 6][bk] = f2b(g1.z); Bs[bn8 + 7][bk] = f2b(g1.w);
            }
            __syncthreads();
            bf16x8_t a = *(bf16x8_t*)&As[wave * 16 + ln][lq * 8];
            for (int nt = 0; nt < 4; nt++) {
                bf16x8_t bf = *(bf16x8_t*)&Bs[nt * 16 + ln][lq * 8];
                acc[nt] = __builtin_amdgcn_mfma_f32_16x16x32_bf16(a, bf, acc[nt], 0, 0, 0);
            }
        }
        for (int nt = 0; nt < 4; nt++) {
            int c = bn + nt * 16 + ln;
            float bv = b_mem[c];
            for (int r = 0; r < 4; r++) {
                int row = wave * 16 + lq * 4 + r;
                int h = c >> 6, d = c & 63;
                unsigned short o = f2b(acc[nt][r] + bv);
                mem_k[((h * 64 + row) << 6) + d] = o;   // [H,M,D]
                mem_v[((h * 64 + d) << 6) + row] = o;   // [H,D,M]
            }
        }
    }
}

// ---- 256x128 bf16 GEMM (r14 structure, verified): 48KB single-buffer,
// 2-barrier drain loop, XCD swizzle, LDS-bounce coalesced epilogue.
// r16: V output range written directly in transposed [B,H,D,T] (vtrans deleted). ----
__global__ __launch_bounds__(512) void gemm512(
    const unsigned short* __restrict__ A,
    const unsigned short* __restrict__ BT,
    const float* __restrict__ bias,
    unsigned short* __restrict__ dq,
    unsigned short* __restrict__ dkv,   // k at +0 ([B,H,T,D]); v at +QSZ ([B,H,D,T])
    int M, int N, int K)   // K == 768 always
{
    __shared__ unsigned short As[16384];  // 256 x 64
    __shared__ unsigned short Bs[8192];   // 128 x 64
    const int t = threadIdx.x;
    const int wave = t >> 6, lane = t & 63;
    const int ln = lane & 15, lq = lane >> 4;
    const int wm = (wave >> 1) * 64, wn = (wave & 1) * 64;

    // bijective XCD remap (576 = 8*72 exact)
    int bid0 = blockIdx.y * gridDim.x + blockIdx.x;
    int bid = (bid0 & 7) * 72 + (bid0 >> 3);
    int by = bid / 18, bx = bid - by * 18;
    const int bm = by * 256, bn = bx * 128;

    f32x4_t acc[4][4];
    for (int i = 0; i < 4; i++)
        for (int j = 0; j < 4; j++) acc[i][j] = (f32x4_t)(0.f);

    const int rl8 = lane >> 3;
    const int swz = ((lane & 7) ^ rl8) * 8;
    const unsigned short* Ap = A + (size_t)(bm + wave * 32 + rl8) * 768 + swz;
    const unsigned short* Bp = BT + (size_t)(bn + wave * 16 + rl8) * 768 + swz;
    unsigned short* asd = &As[wave * 2048];
    unsigned short* bsd = &Bs[wave * 1024];

    const int e0 = (lq ^ (ln & 7)) * 8;
    const int e1 = e0 ^ 32;

    for (int k0 = 0; k0 < 768; k0 += 64) {
        __syncthreads();
        for (int i = 0; i < 4; i++)
            gl16(Ap + (size_t)(i * 8) * 768 + k0, asd + i * 512);
        for (int i = 0; i < 2; i++)
            gl16(Bp + (size_t)(i * 8) * 768 + k0, bsd + i * 512);
        __syncthreads();

        {
            bf16x8_t af[4], bfr[4];
            for (int mt = 0; mt < 4; mt++)
                af[mt] = *(bf16x8_t*)&As[(wm + mt * 16 + ln) * 64 + e0];
            for (int nt = 0; nt < 4; nt++)
                bfr[nt] = *(bf16x8_t*)&Bs[(wn + nt * 16 + ln) * 64 + e0];
            for (int mt = 0; mt < 4; mt++)
                for (int nt = 0; nt < 4; nt++)
                    acc[mt][nt] = __builtin_amdgcn_mfma_f32_16x16x32_bf16(
                        af[mt], bfr[nt], acc[mt][nt], 0, 0, 0);
        }
        {
            bf16x8_t af[4], bfr[4];
            for (int mt = 0; mt < 4; mt++)
                af[mt] = *(bf16x8_t*)&As[(wm + mt * 16 + ln) * 64 + e1];
            for (int nt = 0; nt < 4; nt++)
                bfr[nt] = *(bf16x8_t*)&Bs[(wn + nt * 16 + ln) * 64 + e1];
            for (int mt = 0; mt < 4; mt++)
                for (int nt = 0; nt < 4; nt++)
                    acc[mt][nt] = __builtin_amdgcn_mfma_f32_16x16x32_bf16(
                        af[mt], bfr[nt], acc[mt][nt], 0, 0, 0);
        }
    }

    // ---- LDS-bounce coalesced epilogue ----
    __syncthreads();                       // all waves done reading As/Bs
    unsigned short* slab = &As[wave * 2048];   // wave-private 4KB (32 rows x 64)
    const float QSCALE = 0.125f * 1.44269504088896340736f;
    const int s = bn / 768;                // block-uniform: 768 % 128 == 0
    const int rem0 = bn + wn - s * 768;
    const int h = rem0 >> 6;               // head index (s>=1); rem0 is 64-aligned
    const int bbq = bm >> 10;              // batch (256-row tile never crosses b)
    const int tt0 = (bm & 1023) + wm;
    const int r2 = lane >> 1, half = lane & 1;

    float bv[4];
    for (int nt = 0; nt < 4; nt++) bv[nt] = bias[bn + wn + nt * 16 + ln];

    for (int p = 0; p < 2; p++) {
        // scatter this wave's acc (mt = 2p, 2p+1) into swizzled slab [32][64]
        for (int mt2 = 0; mt2 < 2; mt2++) {
            int mt = p * 2 + mt2;
            for (int nt = 0; nt < 4; nt++) {
                int col = nt * 16 + ln;
                for (int r = 0; r < 4; r++) {
                    int tp = mt2 * 16 + lq * 4 + r;
                    float val = acc[mt][nt][r] + bv[nt];
                    if (s == 0) val *= QSCALE;
                    slab[tp * 64 + ((((col >> 3) ^ (tp & 7)) << 3) | (col & 7))] = f2b(val);
                }
            }
        }
        asm volatile("s_waitcnt lgkmcnt(0)" ::: "memory");  // wave-local slab visible
        SCHED_FENCE();
        if (s == 0) {
            // q: row-gather, coalesced bf16x8 stores
            unsigned short* op = dq + (size_t)(bm + wm + p * 32 + r2) * 768 + bn + wn;
#pragma unroll
            for (int i = 0; i < 4; i++) {
                int c2 = half * 4 + i;
                int g = c2 ^ (r2 & 7);
                *(bf16x8_t*)&op[c2 * 8] = *(bf16x8_t*)&slab[r2 * 64 + g * 8];
            }
        } else if (s == 1) {
            // k: [B,H,T,D], row-gather
            unsigned short* op = dkv +
                (((size_t)(bbq * 12 + h) * 1024 + tt0 + p * 32 + r2) << 6);
#pragma unroll
            for (int i = 0; i < 4; i++) {
                int c2 = half * 4 + i;
                int g = c2 ^ (r2 & 7);
                *(bf16x8_t*)&op[c2 * 8] = *(bf16x8_t*)&slab[r2 * 64 + g * 8];
            }
        } else {
            // v: direct transposed [B,H,D,T] (replaces the vtrans kernel)
            unsigned short* op0 = dkv + (size_t)QSZ + (((size_t)(bbq * 12 + h)) << 16);
            const int tb = tt0 + p * 32;
#pragma unroll
            for (int i = 0; i < 4; i++) {
                int d = (lane >> 2) + i * 16;
                int t0q = (lane & 3) * 8;
                union { bf16x8_t v; unsigned short s8[8]; } u;
#pragma unroll
                for (int j = 0; j < 8; j++) {
                    int tp = t0q + j;
                    u.s8[j] = slab[tp * 64 + ((((d >> 3) ^ (tp & 7)) << 3) | (d & 7))];
                }
                *(bf16x8_t*)&op0[d * 1024 + tb + t0q] = u.v;
            }
        }
        SCHED_FENCE();   // keep p=1 slab writes after p=0 reads (in-order DS per wave)
    }
}

// ---- 128x128 bf16 GEMM, BK=64, XOR-swizzled, double-buffered,
// r12 counted-vmcnt 2-deep pipeline; r14 LDS-bounce f32 epilogue.
// r19: + bijective XCD swizzle (384 = 8*48 exact): the 6 consecutive bids
// sharing one 196KB A-panel land on one XCD's L2 (same verified mechanism
// as gemm512's swizzle). ----
__global__ __launch_bounds__(256) void gemm_bt(
    const unsigned short* __restrict__ A,
    const unsigned short* __restrict__ BT,
    const float* __restrict__ bias,
    float* __restrict__ df,
    int M, int N, int K)   // K == 768 always
{
    __shared__ unsigned short As[2][8192];   // 2 x (128 x 64)
    __shared__ unsigned short Bs[2][8192];
    const int t = threadIdx.x;
    const int wave = t >> 6, lane = t & 63;
    const int ln = lane & 15, lq = lane >> 4;
    const int wm = (wave >> 1) * 64, wn = (wave & 1) * 64;

    // bijective XCD remap (384 = 8*48 exact); bx fastest -> A-panel sharers contiguous
    int bid0 = blockIdx.y * gridDim.x + blockIdx.x;
    int bid = (bid0 & 7) * 48 + (bid0 >> 3);
    int by = bid / 6, bx = bid - by * 6;
    const int bm = by * 128, bn = bx * 128;

    f32x4_t acc[4][4];
    for (int i = 0; i < 4; i++)
        for (int j = 0; j < 4; j++) acc[i][j] = (f32x4_t)(0.f);

    const int rl8 = lane >> 3;
    const int swz = ((lane & 7) ^ rl8) * 8;
    const unsigned short* Ap = A + (size_t)(bm + wave * 32 + rl8) * 768 + swz;
    const unsigned short* Bp = BT + (size_t)(bn + wave * 32 + rl8) * 768 + swz;

    const int e0 = (lq ^ (ln & 7)) * 8;
    const int e1 = e0 ^ 32;

    auto stage = [&](int buf, int k0) {
#pragma unroll
        for (int i = 0; i < 4; i++) {
            gl16(Ap + (size_t)(i * 8) * 768 + k0, &As[buf][wave * 2048 + i * 512]);
            gl16(Bp + (size_t)(i * 8) * 768 + k0, &Bs[buf][wave * 2048 + i * 512]);
        }
    };

    auto compute = [&](const unsigned short* Ac, const unsigned short* Bc) {
        bf16x8_t af0[4], af1[4], bf0[4], bf1[4];
#pragma unroll
        for (int mt = 0; mt < 4; mt++) {
            af0[mt] = *(const bf16x8_t*)&Ac[(wm + mt * 16 + ln) * 64 + e0];
            af1[mt] = *(const bf16x8_t*)&Ac[(wm + mt * 16 + ln) * 64 + e1];
        }
#pragma unroll
        for (int nt = 0; nt < 4; nt++) {
            bf0[nt] = *(const bf16x8_t*)&Bc[(wn + nt * 16 + ln) * 64 + e0];
            bf1[nt] = *(const bf16x8_t*)&Bc[(wn + nt * 16 + ln) * 64 + e1];
        }
        __builtin_amdgcn_s_setprio(1);
#pragma unroll
        for (int mt = 0; mt < 4; mt++)
#pragma unroll
            for (int nt = 0; nt < 4; nt++)
                acc[mt][nt] = __builtin_amdgcn_mfma_f32_16x16x32_bf16(
                    af0[mt], bf0[nt], acc[mt][nt], 0, 0, 0);
#pragma unroll
        for (int mt = 0; mt < 4; mt++)
#pragma unroll
            for (int nt = 0; nt < 4; nt++)
                acc[mt][nt] = __builtin_amdgcn_mfma_f32_16x16x32_bf16(
                    af1[mt], bf1[nt], acc[mt][nt], 0, 0, 0);
        __builtin_amdgcn_s_setprio(0);
    };

    // prologue: tiles 0,1 in flight (16 loads), wait tile 0
    stage(0, 0);
    stage(1, 64);
    SCHED_FENCE();
    asm volatile("s_waitcnt vmcnt(8)" ::: "memory");
    SCHED_FENCE();
    __builtin_amdgcn_s_barrier();
    SCHED_FENCE();

#pragma unroll 2
    for (int tt = 0; tt < 10; ++tt) {
        const int cur = tt & 1;
        compute(&As[cur][0], &Bs[cur][0]);
        SCHED_FENCE();
        __builtin_amdgcn_s_barrier();
        SCHED_FENCE();
        stage(cur, (tt + 2) * 64);
        SCHED_FENCE();
        asm volatile("s_waitcnt vmcnt(8)" ::: "memory");
        SCHED_FENCE();
        __builtin_amdgcn_s_barrier();
        SCHED_FENCE();
    }
    compute(&As[0][0], &Bs[0][0]);
    SCHED_FENCE();
    asm volatile("s_waitcnt vmcnt(0)" ::: "memory");
    SCHED_FENCE();
    __builtin_amdgcn_s_barrier();
    SCHED_FENCE();
    compute(&As[1][0], &Bs[1][0]);

    // ---- LDS-bounce coalesced f32 epilogue ----
    __syncthreads();                           // all waves done with As/Bs
    float* slabf = (float*)&As[0][0] + wave * 2048;   // wave-private 8KB (32 x 64 f32)
    const int r2 = lane >> 1, half = lane & 1;
    float bv[4];
    for (int nt = 0; nt < 4; nt++) bv[nt] = bias[bn + wn + nt * 16 + ln];

    for (int p = 0; p < 2; p++) {
        for (int mt2 = 0; mt2 < 2; mt2++) {
            int mt = p * 2 + mt2;
            for (int nt = 0; nt < 4; nt++) {
                int col = nt * 16 + ln;
                for (int r = 0; r < 4; r++) {
                    int tp = mt2 * 16 + lq * 4 + r;
                    slabf[tp * 64 + ((((col >> 2) ^ (tp & 15)) << 2) | (col & 3))] =
                        acc[mt][nt][r] + bv[nt];
                }
            }
        }
        asm volatile("s_waitcnt lgkmcnt(0)" ::: "memory");
        SCHED_FENCE();
        float* op = df + (size_t)(bm + wm + p * 32 + r2) * 768 + bn + wn;
#pragma unroll
        for (int i = 0; i < 8; i++) {
            int c2 = half * 8 + i;
            int g = c2 ^ (r2 & 15);
            *(float4*)&op[c2 * 4] = *(float4*)&slabf[r2 * 64 + g * 4];
        }
        SCHED_FENCE();
    }
}

// ---- flash attention (r14 version, verified 52.6us in the 234.0us r16 build):
// 512 threads, 8 waves x 16 q-rows, 128-key kt steps, unnormalized exp2
// (scale folded into q), XOR-swizzled LDS. r18's V-direct-from-global variant
// regressed 2.1x: consecutive lanes were 2KB apart (64-way gather/inst). ----
__global__ __launch_bounds__(512) void attn_kernel(
    unsigned short* __restrict__ qio,           // [B,T,768] bf16, in/out (q pre-scaled)
    const unsigned short* __restrict__ k_ws,    // [B,H,T,D] bf16
    const unsigned short* __restrict__ vT_ws,   // [B,H,D,T] bf16 (transposed)
    const unsigned short* __restrict__ mem_k,   // [H,M,D]   bf16
    const unsigned short* __restrict__ mem_v)   // [H,D,M]   bf16
{
    __shared__ unsigned short Qs[8192];   // 128x64; aliased as Ps after frag hoist
    __shared__ unsigned short Ks[8192];   // two 64-key tiles
    __shared__ unsigned short Vs[8192];   // two 64-key tiles (rows = d)
    unsigned short* Ps = Qs;

    const int t = threadIdx.x;
    const int wave = t >> 6, lane = t & 63;
    const int ln = lane & 15, lq = lane >> 4;
    const int rl = lane >> 3;
    const int cl = ((lane & 7) ^ rl) * 8;

    // XCD swizzle: 8 q-tiles of one (b,h) land on one XCD
    int bid = blockIdx.x;
    int xcd = bid & 7, rest = bid >> 3;        // rest 0..95
    int bh = xcd * 12 + (rest >> 3);           // 0..95 == b*NH + h
    int qt = rest & 7;                         // 0..7 (128-row q tiles)
    int b = bh / 12, h = bh - b * 12;

    unsigned short* qp = qio + ((size_t)(b * TT + qt * 128)) * 768 + h * 64;
    const unsigned short* kp = k_ws + (size_t)bh * TT * 64;
    const unsigned short* vp = vT_ws + ((size_t)bh << 16);
    const unsigned short* mkp = mem_k + h * 4096;
    const unsigned short* mvp = mem_v + h * 4096;

    // stage Q (2 slabs per wave), hoist this wave's A-fragments (16 q-rows)
    {
        const unsigned short* qg = qp + (size_t)(wave * 16 + rl) * 768 + cl;
        gl16(qg, &Qs[wave * 1024]);
        gl16(qg + (size_t)8 * 768, &Qs[wave * 1024 + 512]);
    }
    __syncthreads();
    const int e0 = (lq ^ (ln & 7)) * 8;
    const int e1 = ((lq ^ (ln & 7)) ^ 4) * 8;
    bf16x8_t aq0 = *(bf16x8_t*)&Qs[(wave * 16 + ln) * 64 + e0];
    bf16x8_t aq1 = *(bf16x8_t*)&Qs[(wave * 16 + ln) * 64 + e1];

    // staging bases: K slabs s=w*2+i (keys s*8..+8); V slabs: half=s>>3, d-rows (s&7)*8..+8
    const unsigned short* kg = kp + (wave * 16 + rl) * 64 + cl;
    const unsigned short* vg = vp + (size_t)((wave & 3) * 16 + rl) * 1024 + (wave >> 2) * 64 + cl;

    const int hi3 = ln >> 3, lo3 = ln & 7;
    const int pm = (lq & 1) << 2;
    const int pw0 = (wave * 16 + lq * 4) * 64 + lo3;

    float lsum[4] = {0.f, 0.f, 0.f, 0.f};
    f32x4_t accO[4];
    for (int nt = 0; nt < 4; nt++) accO[nt] = (f32x4_t)(0.f);

    for (int kt = 0; kt < 8; kt++) {
        __syncthreads();
        gl16(kg + kt * 8192,        &Ks[wave * 1024]);
        gl16(kg + kt * 8192 + 512,  &Ks[wave * 1024 + 512]);
        gl16(vg + kt * 128,                 &Vs[wave * 1024]);
        gl16(vg + (size_t)8 * 1024 + kt * 128, &Vs[wave * 1024 + 512]);
        __syncthreads();

        for (int half = 0; half < 2; half++) {
            const unsigned short* Kh = &Ks[half * 4096];
            const unsigned short* Vh = &Vs[half * 4096];
            f32x4_t s[4];
            for (int nt = 0; nt < 4; nt++) s[nt] = (f32x4_t)(0.f);
            for (int nt = 0; nt < 4; nt++)
                s[nt] = __builtin_amdgcn_mfma_f32_16x16x32_bf16(
                    aq0, *(bf16x8_t*)&Kh[(nt * 16 + ln) * 64 + e0], s[nt], 0, 0, 0);
            for (int nt = 0; nt < 4; nt++)
                s[nt] = __builtin_amdgcn_mfma_f32_16x16x32_bf16(
                    aq1, *(bf16x8_t*)&Kh[(nt * 16 + ln) * 64 + e1], s[nt], 0, 0, 0);

            for (int nt = 0; nt < 4; nt++) {
                for (int r = 0; r < 4; r++) {
                    float p = __builtin_amdgcn_exp2f(s[nt][r]);
                    lsum[r] += p;
                    int chp = (nt * 2 + hi3) ^ pm ^ r;
                    Ps[pw0 + r * 64 + chp * 8] = f2b_ru(p);
                }
            }
            // Ps slab is wave-private: no barrier needed
            bf16x8_t a0 = *(bf16x8_t*)&Ps[(wave * 16 + ln) * 64 + e0];
            bf16x8_t a1 = *(bf16x8_t*)&Ps[(wave * 16 + ln) * 64 + e1];
            for (int nt = 0; nt < 4; nt++) {
                accO[nt] = __builtin_amdgcn_mfma_f32_16x16x32_bf16(
                    a0, *(bf16x8_t*)&Vh[(nt * 16 + ln) * 64 + e0], accO[nt], 0, 0, 0);
                accO[nt] = __builtin_amdgcn_mfma_f32_16x16x32_bf16(
                    a1, *(bf16x8_t*)&Vh[(nt * 16 + ln) * 64 + e1], accO[nt], 0, 0, 0);
            }
        }
    }

    // memory attention: 64 projected keys (each wave stages 1 slab of K and V)
    __syncthreads();
    gl16(mkp + (wave * 8 + rl) * 64 + cl, &Ks[wave * 512]);
    gl16(mvp + (wave * 8 + rl) * 64 + cl, &Vs[wave * 512]);
    __syncthreads();

    f32x4_t s2[4];
    for (int nt = 0; nt < 4; nt++) s2[nt] = (f32x4_t)(0.f);
    for (int nt = 0; nt < 4; nt++)
        s2[nt] = __builtin_amdgcn_mfma_f32_16x16x32_bf16(
            aq0, *(bf16x8_t*)&Ks[(nt * 16 + ln) * 64 + e0], s2[nt], 0, 0, 0);
    for (int nt = 0; nt < 4; nt++)
        s2[nt] = __builtin_amdgcn_mfma_f32_16x16x32_bf16(
            aq1, *(bf16x8_t*)&Ks[(nt * 16 + ln) * 64 + e1], s2[nt], 0, 0, 0);

    float l2[4] = {0.f, 0.f, 0.f, 0.f};
    for (int nt = 0; nt < 4; nt++) {
        for (int r = 0; r < 4; r++) {
            float p = __builtin_amdgcn_exp2f(s2[nt][r]);
            l2[r] += p;
            int chp = (nt * 2 + hi3) ^ pm ^ r;
            Ps[pw0 + r * 64 + chp * 8] = f2b_ru(p);
        }
    }
    f32x4_t accM[4];
    for (int nt = 0; nt < 4; nt++) accM[nt] = (f32x4_t)(0.f);
    {
        bf16x8_t a0 = *(bf16x8_t*)&Ps[(wave * 16 + ln) * 64 + e0];
        bf16x8_t a1 = *(bf16x8_t*)&Ps[(wave * 16 + ln) * 64 + e1];
        for (int nt = 0; nt < 4; nt++) {
            accM[nt] = __builtin_amdgcn_mfma_f32_16x16x32_bf16(
                a0, *(bf16x8_t*)&Vs[(nt * 16 + ln) * 64 + e0], accM[nt], 0, 0, 0);
            accM[nt] = __builtin_amdgcn_mfma_f32_16x16x32_bf16(
                a1, *(bf16x8_t*)&Vs[(nt * 16 + ln) * 64 + e1], accM[nt], 0, 0, 0);
        }
    }

    float inv[4], inv2[4];
    for (int r = 0; r < 4; r++) {
        float a = lsum[r], c = l2[r];
        a += __shfl_xor(a, 1); a += __shfl_xor(a, 2);
        a += __shfl_xor(a, 4); a += __shfl_xor(a, 8);
        c += __shfl_xor(c, 1); c += __shfl_xor(c, 2);
        c += __shfl_xor(c, 4); c += __shfl_xor(c, 8);
        inv[r] = 1.f / a;
        inv2[r] = 1.f / c;
    }

    for (int nt = 0; nt < 4; nt++) {
        for (int r = 0; r < 4; r++) {
            int lrow = wave * 16 + lq * 4 + r;
            int lcol = nt * 16 + ln;
            float val = accO[nt][r] * inv[r] + accM[nt][r] * inv2[r];
            qp[(size_t)lrow * 768 + lcol] = f2b(val);
        }
    }
}

// ---------------- host ----------------
extern "C" void kernel_launch(void* const* d_in, const int* in_sizes, int n_in,
                              void* d_out, int out_size, void* d_ws, size_t ws_size,
                              hipStream_t stream) {
    const float* x      = (const float*)d_in[0];
    const float* w_qkv  = (const float*)d_in[1];
    const float* b_qkv  = (const float*)d_in[2];
    const float* w_out  = (const float*)d_in[3];
    const float* b_out  = (const float*)d_in[4];
    const float* w_mem  = (const float*)d_in[5];
    const float* b_mem  = (const float*)d_in[6];
    const float* memory = (const float*)d_in[7];

    unsigned short* ws = (unsigned short*)d_ws;
    unsigned short* q_ws   = ws;                         // [B,T,C] bf16; attn in-place
    unsigned short* k_ws   = ws + (size_t)QSZ;           // [B,H,T,D]; vT at +QSZ ([B,H,D,T])
    unsigned short* vT     = ws + 2 * (size_t)QSZ;       // [B,H,D,T] (written by gemm512)
    unsigned short* woutT  = ws + 3 * (size_t)QSZ;       // [768][768] bf16 (N x K)
    unsigned short* mem_k  = woutT + (size_t)EMBED * EMBED;
    unsigned short* mem_v  = mem_k + (size_t)NH * MEMN * HD;

    unsigned short* xb    = (unsigned short*)d_out;      // [8192][768] bf16
    unsigned short* wqkvT = xb + (size_t)QSZ;            // [2304][768] bf16

    // 1) fused prep (cvt + 2 tcvt + memproj)
    prep_kernel<<<PREP_TOTAL, 256, 0, stream>>>(
        x, w_qkv, w_out, memory, w_mem, b_mem, xb, wqkvT, woutT, mem_k, mem_v);

    // 2) QKV projection: q -> q_ws; k -> [B,H,T,D]; v -> [B,H,D,T] (transposed direct)
    gemm512<<<dim3(QKV_N / 128, ROWS / 256), 512, 0, stream>>>(
        xb, wqkvT, b_qkv, q_ws, k_ws, ROWS, QKV_N, EMBED);

    // 3) attention (local flash + memory), in-place over q_ws; 768 blocks x 512 thr
    attn_kernel<<<8 * NH * BB, 512, 0, stream>>>(q_ws, k_ws, vT, mem_k, mem_v);

    // 4) output projection: q_ws(bf16) @ w_out + b_out -> d_out fp32
    gemm_bt<<<dim3(EMBED / 128, ROWS / 128), 256, 0, stream>>>(
        q_ws, woutT, b_out, (float*)d_out, ROWS, EMBED, EMBED);
}

// Round 10
// 224.727 us; speedup vs baseline: 1.3271x; 1.0382x over previous
//
#include <hip/hip_runtime.h>

#define EMBED 768
#define NH 12
#define HD 64
#define MEMN 64
#define BB 8
#define TT 1024
#define ROWS 8192
#define QKV_N 2304
#define QSZ 6291456           // B*T*C = B*NH*TT*HD (elements)

typedef short bf16x8_t __attribute__((ext_vector_type(8)));
typedef float f32x4_t __attribute__((ext_vector_type(4)));

__device__ __forceinline__ unsigned short f2b(float f){
    union { float f; unsigned int i; } v; v.f = f;
    unsigned int x = v.i;
    unsigned int r = x + 0x7fffu + ((x >> 16) & 1u);
    return (unsigned short)(r >> 16);
}
// round-half-up convert for non-negative values (softmax p)
__device__ __forceinline__ unsigned short f2b_ru(float f){
    union { float f; unsigned int i; } v; v.f = f;
    return (unsigned short)((v.i + 0x8000u) >> 16);
}

// async global->LDS, 16B per lane; lds base must be wave-uniform (lane*16 implicit)
__device__ __forceinline__ void gl16(const unsigned short* g, unsigned short* l){
    __builtin_amdgcn_global_load_lds(
        (const __attribute__((address_space(1))) void*)g,
        (__attribute__((address_space(3))) void*)l,
        16, 0, 0);
}

#define SCHED_FENCE() __builtin_amdgcn_sched_barrier(0)

// ---- fused prep: x cvt + w_qkv tcvt + w_out tcvt + memproj (one graph node) ----
#define PREP_CVT   3072
#define PREP_TQKV  4800
#define PREP_TOUT  5376
#define PREP_TOTAL 5388

__global__ __launch_bounds__(256) void prep_kernel(
    const float* __restrict__ x,
    const float* __restrict__ w_qkv,
    const float* __restrict__ w_out,
    const float* __restrict__ memory,
    const float* __restrict__ w_mem,
    const float* __restrict__ b_mem,
    unsigned short* __restrict__ xb,
    unsigned short* __restrict__ wqkvT,
    unsigned short* __restrict__ woutT,
    unsigned short* __restrict__ mem_k,
    unsigned short* __restrict__ mem_v)
{
    __shared__ unsigned short pool[5120];
    const int bid = blockIdx.x;
    const int t = threadIdx.x;

    if (bid < PREP_CVT) {
        int i = bid * 2048 + t * 8;
        float4 f0 = *(const float4*)&x[i];
        float4 f1 = *(const float4*)&x[i + 4];
        union { bf16x8_t v; unsigned short s[8]; } u;
        u.s[0] = f2b(f0.x); u.s[1] = f2b(f0.y); u.s[2] = f2b(f0.z); u.s[3] = f2b(f0.w);
        u.s[4] = f2b(f1.x); u.s[5] = f2b(f1.y); u.s[6] = f2b(f1.z); u.s[7] = f2b(f1.w);
        *(bf16x8_t*)&xb[i] = u.v;
    } else if (bid < PREP_TOUT) {
        const float* in; unsigned short* out; int R, C, loc;
        if (bid < PREP_TQKV) { in = w_qkv; out = wqkvT; R = EMBED; C = QKV_N; loc = bid - PREP_CVT; }
        else                 { in = w_out; out = woutT; R = EMBED; C = EMBED; loc = bid - PREP_TQKV; }
        int nbc = C / 32;
        int bc = (loc % nbc) * 32, br = (loc / nbc) * 32;
        unsigned short (*tile)[33] = (unsigned short(*)[33])pool;
        int lr = t >> 5, lc = t & 31;
        for (int i = 0; i < 4; i++) {
            int r = lr + i * 8;
            tile[r][lc] = f2b(in[(size_t)(br + r) * C + bc + lc]);
        }
        __syncthreads();
        for (int i = 0; i < 4; i++) {
            int r = lr + i * 8;
            out[(size_t)(bc + r) * R + br + lc] = tile[lc][r];
        }
    } else {
        unsigned short (*As)[40] = (unsigned short(*)[40])pool;
        unsigned short (*Bs)[40] = (unsigned short(*)[40])(pool + 2560);
        int wave = t >> 6, lane = t & 63;
        int ln = lane & 15, lq = lane >> 4;
        int bn = (bid - PREP_TOUT) * 64;
        const int K = EMBED, N = EMBED;

        f32x4_t acc[4];
        for (int i = 0; i < 4; i++) acc[i] = (f32x4_t)(0.f);
        int sm = t >> 2, sk = (t & 3) * 8;
        int bk = t >> 3, bn8 = (t & 7) * 8;

        for (int k0 = 0; k0 < K; k0 += 32) {
            __syncthreads();
            {
                float4 f0 = *(const float4*)&memory[(size_t)sm * K + k0 + sk];
                float4 f1 = *(const float4*)&memory[(size_t)sm * K + k0 + sk + 4];
                unsigned short* ap = &As[sm][sk];
                ap[0] = f2b(f0.x); ap[1] = f2b(f0.y); ap[2] = f2b(f0.z); ap[3] = f2b(f0.w);
                ap[4] = f2b(f1.x); ap[5] = f2b(f1.y); ap[6] = f2b(f1.z); ap[7] = f2b(f1.w);
            }
            {
                float4 g0 = *(const float4*)&w_mem[(size_t)(k0 + bk) * N + bn + bn8];
                float4 g1 = *(const float4*)&w_mem[(size_t)(k0 + bk) * N + bn + bn8 + 4];
                Bs[bn8 + 0][bk] = f2b(g0.x); Bs[bn8 + 1][bk] = f2b(g0.y);
                Bs[bn8 + 2][bk] = f2b(g0.z); Bs[bn8 + 3][bk] = f2b(g0.w);
                Bs[bn8 + 4][bk] = f2b(g1.x); Bs[bn8 + 5][bk] = f2b(g1.y);
                Bs[bn8 + 6][bk] = f2b(g1.z); Bs[bn8 + 7][bk] = f2b(g1.w);
            }
            __syncthreads();
            bf16x8_t a = *(bf16x8_t*)&As[wave * 16 + ln][lq * 8];
            for (int nt = 0; nt < 4; nt++) {
                bf16x8_t bf = *(bf16x8_t*)&Bs[nt * 16 + ln][lq * 8];
                acc[nt] = __builtin_amdgcn_mfma_f32_16x16x32_bf16(a, bf, acc[nt], 0, 0, 0);
            }
        }
        for (int nt = 0; nt < 4; nt++) {
            int c = bn + nt * 16 + ln;
            float bv = b_mem[c];
            for (int r = 0; r < 4; r++) {
                int row = wave * 16 + lq * 4 + r;
                int h = c >> 6, d = c & 63;
                unsigned short o = f2b(acc[nt][r] + bv);
                mem_k[((h * 64 + row) << 6) + d] = o;   // [H,M,D]
                mem_v[((h * 64 + d) << 6) + row] = o;   // [H,D,M]
            }
        }
    }
}

// ---- 256x128 bf16 GEMM (r14 structure, verified): 48KB single-buffer,
// 2-barrier drain loop, XCD swizzle, LDS-bounce coalesced epilogue.
// r16: V output range written directly in transposed [B,H,D,T] (vtrans deleted). ----
__global__ __launch_bounds__(512) void gemm512(
    const unsigned short* __restrict__ A,
    const unsigned short* __restrict__ BT,
    const float* __restrict__ bias,
    unsigned short* __restrict__ dq,
    unsigned short* __restrict__ dkv,   // k at +0 ([B,H,T,D]); v at +QSZ ([B,H,D,T])
    int M, int N, int K)   // K == 768 always
{
    __shared__ unsigned short As[16384];  // 256 x 64
    __shared__ unsigned short Bs[8192];   // 128 x 64
    const int t = threadIdx.x;
    const int wave = t >> 6, lane = t & 63;
    const int ln = lane & 15, lq = lane >> 4;
    const int wm = (wave >> 1) * 64, wn = (wave & 1) * 64;

    // bijective XCD remap (576 = 8*72 exact)
    int bid0 = blockIdx.y * gridDim.x + blockIdx.x;
    int bid = (bid0 & 7) * 72 + (bid0 >> 3);
    int by = bid / 18, bx = bid - by * 18;
    const int bm = by * 256, bn = bx * 128;

    f32x4_t acc[4][4];
    for (int i = 0; i < 4; i++)
        for (int j = 0; j < 4; j++) acc[i][j] = (f32x4_t)(0.f);

    const int rl8 = lane >> 3;
    const int swz = ((lane & 7) ^ rl8) * 8;
    const unsigned short* Ap = A + (size_t)(bm + wave * 32 + rl8) * 768 + swz;
    const unsigned short* Bp = BT + (size_t)(bn + wave * 16 + rl8) * 768 + swz;
    unsigned short* asd = &As[wave * 2048];
    unsigned short* bsd = &Bs[wave * 1024];

    const int e0 = (lq ^ (ln & 7)) * 8;
    const int e1 = e0 ^ 32;

    for (int k0 = 0; k0 < 768; k0 += 64) {
        __syncthreads();
        for (int i = 0; i < 4; i++)
            gl16(Ap + (size_t)(i * 8) * 768 + k0, asd + i * 512);
        for (int i = 0; i < 2; i++)
            gl16(Bp + (size_t)(i * 8) * 768 + k0, bsd + i * 512);
        __syncthreads();

        {
            bf16x8_t af[4], bfr[4];
            for (int mt = 0; mt < 4; mt++)
                af[mt] = *(bf16x8_t*)&As[(wm + mt * 16 + ln) * 64 + e0];
            for (int nt = 0; nt < 4; nt++)
                bfr[nt] = *(bf16x8_t*)&Bs[(wn + nt * 16 + ln) * 64 + e0];
            for (int mt = 0; mt < 4; mt++)
                for (int nt = 0; nt < 4; nt++)
                    acc[mt][nt] = __builtin_amdgcn_mfma_f32_16x16x32_bf16(
                        af[mt], bfr[nt], acc[mt][nt], 0, 0, 0);
        }
        {
            bf16x8_t af[4], bfr[4];
            for (int mt = 0; mt < 4; mt++)
                af[mt] = *(bf16x8_t*)&As[(wm + mt * 16 + ln) * 64 + e1];
            for (int nt = 0; nt < 4; nt++)
                bfr[nt] = *(bf16x8_t*)&Bs[(wn + nt * 16 + ln) * 64 + e1];
            for (int mt = 0; mt < 4; mt++)
                for (int nt = 0; nt < 4; nt++)
                    acc[mt][nt] = __builtin_amdgcn_mfma_f32_16x16x32_bf16(
                        af[mt], bfr[nt], acc[mt][nt], 0, 0, 0);
        }
    }

    // ---- LDS-bounce coalesced epilogue ----
    __syncthreads();                       // all waves done reading As/Bs
    unsigned short* slab = &As[wave * 2048];   // wave-private 4KB (32 rows x 64)
    const float QSCALE = 0.125f * 1.44269504088896340736f;
    const int s = bn / 768;                // block-uniform: 768 % 128 == 0
    const int rem0 = bn + wn - s * 768;
    const int h = rem0 >> 6;               // head index (s>=1); rem0 is 64-aligned
    const int bbq = bm >> 10;              // batch (256-row tile never crosses b)
    const int tt0 = (bm & 1023) + wm;
    const int r2 = lane >> 1, half = lane & 1;

    float bv[4];
    for (int nt = 0; nt < 4; nt++) bv[nt] = bias[bn + wn + nt * 16 + ln];

    for (int p = 0; p < 2; p++) {
        // scatter this wave's acc (mt = 2p, 2p+1) into swizzled slab [32][64]
        for (int mt2 = 0; mt2 < 2; mt2++) {
            int mt = p * 2 + mt2;
            for (int nt = 0; nt < 4; nt++) {
                int col = nt * 16 + ln;
                for (int r = 0; r < 4; r++) {
                    int tp = mt2 * 16 + lq * 4 + r;
                    float val = acc[mt][nt][r] + bv[nt];
                    if (s == 0) val *= QSCALE;
                    slab[tp * 64 + ((((col >> 3) ^ (tp & 7)) << 3) | (col & 7))] = f2b(val);
                }
            }
        }
        asm volatile("s_waitcnt lgkmcnt(0)" ::: "memory");  // wave-local slab visible
        SCHED_FENCE();
        if (s == 0) {
            // q: row-gather, coalesced bf16x8 stores
            unsigned short* op = dq + (size_t)(bm + wm + p * 32 + r2) * 768 + bn + wn;
#pragma unroll
            for (int i = 0; i < 4; i++) {
                int c2 = half * 4 + i;
                int g = c2 ^ (r2 & 7);
                *(bf16x8_t*)&op[c2 * 8] = *(bf16x8_t*)&slab[r2 * 64 + g * 8];
            }
        } else if (s == 1) {
            // k: [B,H,T,D], row-gather
            unsigned short* op = dkv +
                (((size_t)(bbq * 12 + h) * 1024 + tt0 + p * 32 + r2) << 6);
#pragma unroll
            for (int i = 0; i < 4; i++) {
                int c2 = half * 4 + i;
                int g = c2 ^ (r2 & 7);
                *(bf16x8_t*)&op[c2 * 8] = *(bf16x8_t*)&slab[r2 * 64 + g * 8];
            }
        } else {
            // v: direct transposed [B,H,D,T] (replaces the vtrans kernel)
            unsigned short* op0 = dkv + (size_t)QSZ + (((size_t)(bbq * 12 + h)) << 16);
            const int tb = tt0 + p * 32;
#pragma unroll
            for (int i = 0; i < 4; i++) {
                int d = (lane >> 2) + i * 16;
                int t0q = (lane & 3) * 8;
                union { bf16x8_t v; unsigned short s8[8]; } u;
#pragma unroll
                for (int j = 0; j < 8; j++) {
                    int tp = t0q + j;
                    u.s8[j] = slab[tp * 64 + ((((d >> 3) ^ (tp & 7)) << 3) | (d & 7))];
                }
                *(bf16x8_t*)&op0[d * 1024 + tb + t0q] = u.v;
            }
        }
        SCHED_FENCE();   // keep p=1 slab writes after p=0 reads (in-order DS per wave)
    }
}

// ---- 128x128 bf16 GEMM, BK=64, XOR-swizzled, double-buffered,
// r12 counted-vmcnt 2-deep pipeline; r14 LDS-bounce f32 epilogue.
// r19: + bijective XCD swizzle (384 = 8*48 exact). ----
__global__ __launch_bounds__(256) void gemm_bt(
    const unsigned short* __restrict__ A,
    const unsigned short* __restrict__ BT,
    const float* __restrict__ bias,
    float* __restrict__ df,
    int M, int N, int K)   // K == 768 always
{
    __shared__ unsigned short As[2][8192];   // 2 x (128 x 64)
    __shared__ unsigned short Bs[2][8192];
    const int t = threadIdx.x;
    const int wave = t >> 6, lane = t & 63;
    const int ln = lane & 15, lq = lane >> 4;
    const int wm = (wave >> 1) * 64, wn = (wave & 1) * 64;

    // bijective XCD remap (384 = 8*48 exact); bx fastest -> A-panel sharers contiguous
    int bid0 = blockIdx.y * gridDim.x + blockIdx.x;
    int bid = (bid0 & 7) * 48 + (bid0 >> 3);
    int by = bid / 6, bx = bid - by * 6;
    const int bm = by * 128, bn = bx * 128;

    f32x4_t acc[4][4];
    for (int i = 0; i < 4; i++)
        for (int j = 0; j < 4; j++) acc[i][j] = (f32x4_t)(0.f);

    const int rl8 = lane >> 3;
    const int swz = ((lane & 7) ^ rl8) * 8;
    const unsigned short* Ap = A + (size_t)(bm + wave * 32 + rl8) * 768 + swz;
    const unsigned short* Bp = BT + (size_t)(bn + wave * 32 + rl8) * 768 + swz;

    const int e0 = (lq ^ (ln & 7)) * 8;
    const int e1 = e0 ^ 32;

    auto stage = [&](int buf, int k0) {
#pragma unroll
        for (int i = 0; i < 4; i++) {
            gl16(Ap + (size_t)(i * 8) * 768 + k0, &As[buf][wave * 2048 + i * 512]);
            gl16(Bp + (size_t)(i * 8) * 768 + k0, &Bs[buf][wave * 2048 + i * 512]);
        }
    };

    auto compute = [&](const unsigned short* Ac, const unsigned short* Bc) {
        bf16x8_t af0[4], af1[4], bf0[4], bf1[4];
#pragma unroll
        for (int mt = 0; mt < 4; mt++) {
            af0[mt] = *(const bf16x8_t*)&Ac[(wm + mt * 16 + ln) * 64 + e0];
            af1[mt] = *(const bf16x8_t*)&Ac[(wm + mt * 16 + ln) * 64 + e1];
        }
#pragma unroll
        for (int nt = 0; nt < 4; nt++) {
            bf0[nt] = *(const bf16x8_t*)&Bc[(wn + nt * 16 + ln) * 64 + e0];
            bf1[nt] = *(const bf16x8_t*)&Bc[(wn + nt * 16 + ln) * 64 + e1];
        }
        __builtin_amdgcn_s_setprio(1);
#pragma unroll
        for (int mt = 0; mt < 4; mt++)
#pragma unroll
            for (int nt = 0; nt < 4; nt++)
                acc[mt][nt] = __builtin_amdgcn_mfma_f32_16x16x32_bf16(
                    af0[mt], bf0[nt], acc[mt][nt], 0, 0, 0);
#pragma unroll
        for (int mt = 0; mt < 4; mt++)
#pragma unroll
            for (int nt = 0; nt < 4; nt++)
                acc[mt][nt] = __builtin_amdgcn_mfma_f32_16x16x32_bf16(
                    af1[mt], bf1[nt], acc[mt][nt], 0, 0, 0);
        __builtin_amdgcn_s_setprio(0);
    };

    // prologue: tiles 0,1 in flight (16 loads), wait tile 0
    stage(0, 0);
    stage(1, 64);
    SCHED_FENCE();
    asm volatile("s_waitcnt vmcnt(8)" ::: "memory");
    SCHED_FENCE();
    __builtin_amdgcn_s_barrier();
    SCHED_FENCE();

#pragma unroll 2
    for (int tt = 0; tt < 10; ++tt) {
        const int cur = tt & 1;
        compute(&As[cur][0], &Bs[cur][0]);
        SCHED_FENCE();
        __builtin_amdgcn_s_barrier();
        SCHED_FENCE();
        stage(cur, (tt + 2) * 64);
        SCHED_FENCE();
        asm volatile("s_waitcnt vmcnt(8)" ::: "memory");
        SCHED_FENCE();
        __builtin_amdgcn_s_barrier();
        SCHED_FENCE();
    }
    compute(&As[0][0], &Bs[0][0]);
    SCHED_FENCE();
    asm volatile("s_waitcnt vmcnt(0)" ::: "memory");
    SCHED_FENCE();
    __builtin_amdgcn_s_barrier();
    SCHED_FENCE();
    compute(&As[1][0], &Bs[1][0]);

    // ---- LDS-bounce coalesced f32 epilogue ----
    __syncthreads();                           // all waves done with As/Bs
    float* slabf = (float*)&As[0][0] + wave * 2048;   // wave-private 8KB (32 x 64 f32)
    const int r2 = lane >> 1, half = lane & 1;
    float bv[4];
    for (int nt = 0; nt < 4; nt++) bv[nt] = bias[bn + wn + nt * 16 + ln];

    for (int p = 0; p < 2; p++) {
        for (int mt2 = 0; mt2 < 2; mt2++) {
            int mt = p * 2 + mt2;
            for (int nt = 0; nt < 4; nt++) {
                int col = nt * 16 + ln;
                for (int r = 0; r < 4; r++) {
                    int tp = mt2 * 16 + lq * 4 + r;
                    slabf[tp * 64 + ((((col >> 2) ^ (tp & 15)) << 2) | (col & 3))] =
                        acc[mt][nt][r] + bv[nt];
                }
            }
        }
        asm volatile("s_waitcnt lgkmcnt(0)" ::: "memory");
        SCHED_FENCE();
        float* op = df + (size_t)(bm + wm + p * 32 + r2) * 768 + bn + wn;
#pragma unroll
        for (int i = 0; i < 8; i++) {
            int c2 = half * 8 + i;
            int g = c2 ^ (r2 & 15);
            *(float4*)&op[c2 * 4] = *(float4*)&slabf[r2 * 64 + g * 4];
        }
        SCHED_FENCE();
    }
}

// ---- flash attention r20: r14 structure (512 thr, 8 waves x 16 q-rows,
// 48KB LDS, 24 waves/CU) with SWAPPED QK^T (partial T12).
// Compute S^T = mfma(K_frag, Q_frag): A/B fragment lane maps are identical
// for 16x16x32, so aq/Kh reads are byte-identical to r14; output becomes
// col=q=ln, row=k=lq*4+r. Lane then owns P[q=ln] at k=nt*16+lq*4+{0..3} —
// 4 CONTIGUOUS elements -> one 8B packed write per nt (8 ds_write_b64/kt
// vs 32 ds_write_b16). Write chunk (nt*2+(lq>>1))^(ln&7) at 16B granularity
// is exactly inverted by the existing e0/e1 read expressions (chunk lq, 4+lq),
// so PV A-frag reads are the unchanged a0/a1 lines; V depth pairing matches
// (both deswizzle to k=lq*8+j). Write banks 2-way (free), reads unchanged.
// lsum collapses to one scalar/lane (q=ln): shfl_xor(16,32) reduce once at
// end + 4 __shfl to redistribute to accO row indexing. DS/wave/kt 618->~490
// cyc (the P-write path was ~30% of the measured DS-port floor). ----
__global__ __launch_bounds__(512) void attn_kernel(
    unsigned short* __restrict__ qio,           // [B,T,768] bf16, in/out (q pre-scaled)
    const unsigned short* __restrict__ k_ws,    // [B,H,T,D] bf16
    const unsigned short* __restrict__ vT_ws,   // [B,H,D,T] bf16 (transposed)
    const unsigned short* __restrict__ mem_k,   // [H,M,D]   bf16
    const unsigned short* __restrict__ mem_v)   // [H,D,M]   bf16
{
    __shared__ unsigned short Qs[8192];   // 128x64; aliased as Ps after frag hoist
    __shared__ unsigned short Ks[8192];   // two 64-key tiles
    __shared__ unsigned short Vs[8192];   // two 64-key tiles (rows = d)
    unsigned short* Ps = Qs;

    const int t = threadIdx.x;
    const int wave = t >> 6, lane = t & 63;
    const int ln = lane & 15, lq = lane >> 4;
    const int rl = lane >> 3;
    const int cl = ((lane & 7) ^ rl) * 8;

    // XCD swizzle: 8 q-tiles of one (b,h) land on one XCD
    int bid = blockIdx.x;
    int xcd = bid & 7, rest = bid >> 3;        // rest 0..95
    int bh = xcd * 12 + (rest >> 3);           // 0..95 == b*NH + h
    int qt = rest & 7;                         // 0..7 (128-row q tiles)
    int b = bh / 12, h = bh - b * 12;

    unsigned short* qp = qio + ((size_t)(b * TT + qt * 128)) * 768 + h * 64;
    const unsigned short* kp = k_ws + (size_t)bh * TT * 64;
    const unsigned short* vp = vT_ws + ((size_t)bh << 16);
    const unsigned short* mkp = mem_k + h * 4096;
    const unsigned short* mvp = mem_v + h * 4096;

    // stage Q (2 slabs per wave), hoist this wave's A-fragments (16 q-rows)
    {
        const unsigned short* qg = qp + (size_t)(wave * 16 + rl) * 768 + cl;
        gl16(qg, &Qs[wave * 1024]);
        gl16(qg + (size_t)8 * 768, &Qs[wave * 1024 + 512]);
    }
    __syncthreads();
    const int e0 = (lq ^ (ln & 7)) * 8;
    const int e1 = ((lq ^ (ln & 7)) ^ 4) * 8;
    bf16x8_t aq0 = *(bf16x8_t*)&Qs[(wave * 16 + ln) * 64 + e0];
    bf16x8_t aq1 = *(bf16x8_t*)&Qs[(wave * 16 + ln) * 64 + e1];

    // staging bases: K slabs s=w*2+i (keys s*8..+8); V slabs: half=s>>3, d-rows (s&7)*8..+8
    const unsigned short* kg = kp + (wave * 16 + rl) * 64 + cl;
    const unsigned short* vg = vp + (size_t)((wave & 3) * 16 + rl) * 1024 + (wave >> 2) * 64 + cl;

    // swapped-P layout constants: row q = wave*16+ln, 8 chunks of 8 elems,
    // write chunk = (nt*2 + (lq>>1)) ^ (ln&7), 8B half = lq&1
    const int ln7 = ln & 7;
    const int lqh = lq >> 1, lql4 = (lq & 1) * 4;
    const int prow = (wave * 16 + ln) * 64;

    float lsum = 0.f;
    f32x4_t accO[4];
    for (int nt = 0; nt < 4; nt++) accO[nt] = (f32x4_t)(0.f);

    for (int kt = 0; kt < 8; kt++) {
        __syncthreads();
        gl16(kg + kt * 8192,        &Ks[wave * 1024]);
        gl16(kg + kt * 8192 + 512,  &Ks[wave * 1024 + 512]);
        gl16(vg + kt * 128,                 &Vs[wave * 1024]);
        gl16(vg + (size_t)8 * 1024 + kt * 128, &Vs[wave * 1024 + 512]);
        __syncthreads();

        for (int half = 0; half < 2; half++) {
            const unsigned short* Kh = &Ks[half * 4096];
            const unsigned short* Vh = &Vs[half * 4096];
            f32x4_t s[4];
            for (int nt = 0; nt < 4; nt++) s[nt] = (f32x4_t)(0.f);
            // swapped: A = K fragment, B = Q fragment -> S^T[k][q]
            for (int nt = 0; nt < 4; nt++)
                s[nt] = __builtin_amdgcn_mfma_f32_16x16x32_bf16(
                    *(bf16x8_t*)&Kh[(nt * 16 + ln) * 64 + e0], aq0, s[nt], 0, 0, 0);
            for (int nt = 0; nt < 4; nt++)
                s[nt] = __builtin_amdgcn_mfma_f32_16x16x32_bf16(
                    *(bf16x8_t*)&Kh[(nt * 16 + ln) * 64 + e1], aq1, s[nt], 0, 0, 0);

            for (int nt = 0; nt < 4; nt++) {
                union { unsigned short u[4]; unsigned long long ll; } pk;
#pragma unroll
                for (int r = 0; r < 4; r++) {
                    float p = __builtin_amdgcn_exp2f(s[nt][r]);
                    lsum += p;
                    pk.u[r] = f2b_ru(p);
                }
                *(unsigned long long*)&Ps[prow + (((nt * 2 + lqh) ^ ln7) << 3) + lql4] = pk.ll;
            }
            // Ps slab is wave-private: no barrier needed
            bf16x8_t a0 = *(bf16x8_t*)&Ps[prow + e0];
            bf16x8_t a1 = *(bf16x8_t*)&Ps[prow + e1];
            for (int nt = 0; nt < 4; nt++) {
                accO[nt] = __builtin_amdgcn_mfma_f32_16x16x32_bf16(
                    a0, *(bf16x8_t*)&Vh[(nt * 16 + ln) * 64 + e0], accO[nt], 0, 0, 0);
                accO[nt] = __builtin_amdgcn_mfma_f32_16x16x32_bf16(
                    a1, *(bf16x8_t*)&Vh[(nt * 16 + ln) * 64 + e1], accO[nt], 0, 0, 0);
            }
        }
    }

    // memory attention: 64 projected keys (each wave stages 1 slab of K and V)
    __syncthreads();
    gl16(mkp + (wave * 8 + rl) * 64 + cl, &Ks[wave * 512]);
    gl16(mvp + (wave * 8 + rl) * 64 + cl, &Vs[wave * 512]);
    __syncthreads();

    float l2 = 0.f;
    f32x4_t accM[4];
    for (int nt = 0; nt < 4; nt++) accM[nt] = (f32x4_t)(0.f);
    {
        f32x4_t s2[4];
        for (int nt = 0; nt < 4; nt++) s2[nt] = (f32x4_t)(0.f);
        for (int nt = 0; nt < 4; nt++)
            s2[nt] = __builtin_amdgcn_mfma_f32_16x16x32_bf16(
                *(bf16x8_t*)&Ks[(nt * 16 + ln) * 64 + e0], aq0, s2[nt], 0, 0, 0);
        for (int nt = 0; nt < 4; nt++)
            s2[nt] = __builtin_amdgcn_mfma_f32_16x16x32_bf16(
                *(bf16x8_t*)&Ks[(nt * 16 + ln) * 64 + e1], aq1, s2[nt], 0, 0, 0);

        for (int nt = 0; nt < 4; nt++) {
            union { unsigned short u[4]; unsigned long long ll; } pk;
#pragma unroll
            for (int r = 0; r < 4; r++) {
                float p = __builtin_amdgcn_exp2f(s2[nt][r]);
                l2 += p;
                pk.u[r] = f2b_ru(p);
            }
            *(unsigned long long*)&Ps[prow + (((nt * 2 + lqh) ^ ln7) << 3) + lql4] = pk.ll;
        }
        bf16x8_t a0 = *(bf16x8_t*)&Ps[prow + e0];
        bf16x8_t a1 = *(bf16x8_t*)&Ps[prow + e1];
        for (int nt = 0; nt < 4; nt++) {
            accM[nt] = __builtin_amdgcn_mfma_f32_16x16x32_bf16(
                a0, *(bf16x8_t*)&Vs[(nt * 16 + ln) * 64 + e0], accM[nt], 0, 0, 0);
            accM[nt] = __builtin_amdgcn_mfma_f32_16x16x32_bf16(
                a1, *(bf16x8_t*)&Vs[(nt * 16 + ln) * 64 + e1], accM[nt], 0, 0, 0);
        }
    }

    // reduce lsum/l2 across the 4 lq copies of each q=ln, then redistribute
    // to the accO/accM row indexing (row q_local = lq*4+r held at lane lq*4+r)
    lsum += __shfl_xor(lsum, 16);
    lsum += __shfl_xor(lsum, 32);
    l2   += __shfl_xor(l2, 16);
    l2   += __shfl_xor(l2, 32);
    float invq  = 1.f / lsum;
    float inv2q = 1.f / l2;
    float invr[4], inv2r[4];
#pragma unroll
    for (int r = 0; r < 4; r++) {
        invr[r]  = __shfl(invq,  lq * 4 + r);
        inv2r[r] = __shfl(inv2q, lq * 4 + r);
    }

    for (int nt = 0; nt < 4; nt++) {
        for (int r = 0; r < 4; r++) {
            int lrow = wave * 16 + lq * 4 + r;
            int lcol = nt * 16 + ln;
            float val = accO[nt][r] * invr[r] + accM[nt][r] * inv2r[r];
            qp[(size_t)lrow * 768 + lcol] = f2b(val);
        }
    }
}

// ---------------- host ----------------
extern "C" void kernel_launch(void* const* d_in, const int* in_sizes, int n_in,
                              void* d_out, int out_size, void* d_ws, size_t ws_size,
                              hipStream_t stream) {
    const float* x      = (const float*)d_in[0];
    const float* w_qkv  = (const float*)d_in[1];
    const float* b_qkv  = (const float*)d_in[2];
    const float* w_out  = (const float*)d_in[3];
    const float* b_out  = (const float*)d_in[4];
    const float* w_mem  = (const float*)d_in[5];
    const float* b_mem  = (const float*)d_in[6];
    const float* memory = (const float*)d_in[7];

    unsigned short* ws = (unsigned short*)d_ws;
    unsigned short* q_ws   = ws;                         // [B,T,C] bf16; attn in-place
    unsigned short* k_ws   = ws + (size_t)QSZ;           // [B,H,T,D]; vT at +QSZ ([B,H,D,T])
    unsigned short* vT     = ws + 2 * (size_t)QSZ;       // [B,H,D,T] (written by gemm512)
    unsigned short* woutT  = ws + 3 * (size_t)QSZ;       // [768][768] bf16 (N x K)
    unsigned short* mem_k  = woutT + (size_t)EMBED * EMBED;
    unsigned short* mem_v  = mem_k + (size_t)NH * MEMN * HD;

    unsigned short* xb    = (unsigned short*)d_out;      // [8192][768] bf16
    unsigned short* wqkvT = xb + (size_t)QSZ;            // [2304][768] bf16

    // 1) fused prep (cvt + 2 tcvt + memproj)
    prep_kernel<<<PREP_TOTAL, 256, 0, stream>>>(
        x, w_qkv, w_out, memory, w_mem, b_mem, xb, wqkvT, woutT, mem_k, mem_v);

    // 2) QKV projection: q -> q_ws; k -> [B,H,T,D]; v -> [B,H,D,T] (transposed direct)
    gemm512<<<dim3(QKV_N / 128, ROWS / 256), 512, 0, stream>>>(
        xb, wqkvT, b_qkv, q_ws, k_ws, ROWS, QKV_N, EMBED);

    // 3) attention (local flash + memory), in-place over q_ws; 768 blocks x 512 thr
    attn_kernel<<<8 * NH * BB, 512, 0, stream>>>(q_ws, k_ws, vT, mem_k, mem_v);

    // 4) output projection: q_ws(bf16) @ w_out + b_out -> d_out fp32
    gemm_bt<<<dim3(EMBED / 128, ROWS / 128), 256, 0, stream>>>(
        q_ws, woutT, b_out, (float*)d_out, ROWS, EMBED, EMBED);
}